// Round 14
// baseline (1399.520 us; speedup 1.0000x reference)
//
#include <hip/hip_runtime.h>

typedef unsigned short u16;
typedef unsigned int   u32;
typedef __attribute__((ext_vector_type(8))) short  short8;
typedef __attribute__((ext_vector_type(8))) unsigned short ushort8;
typedef __attribute__((ext_vector_type(4))) float  f32x4;

#define NT 1024      // timesteps
#define NN 33        // nodes
#define NE 97        // edges

__device__ __forceinline__ float b2f(u16 u){ return __uint_as_float(((u32)u)<<16); }
__device__ __forceinline__ u16 f2b(float f){
    u32 x = __float_as_uint(f);
    return (u16)((x + 0x7fffu + ((x>>16)&1u)) >> 16);
}
__device__ __forceinline__ float sigm(float x){ return 1.f/(1.f+__expf(-x)); }
__device__ __forceinline__ float tanh_(float x){ float e=__expf(2.f*x); return 1.f - 2.f/(e+1.f); }

// ---------------------------------------------------------------------------
// convert: per-block dtype detection; block 0 publishes flag (0=bf16, 1=fp32).
// ---------------------------------------------------------------------------
struct ConvArgs { const void* src[22]; int n[22]; int off[22]; };
__global__ void convert_kernel(ConvArgs a, const u32* raw, int* flag, u16* blob){
    __shared__ int s_isf32;
    if (threadIdx.x==0){
        int hits=0;
        for (int k=0;k<256;k++){
            u32 w = raw[k];
            u32 e = (w>>7)&0xffu;
            if (e>=96u && e<=126u) hits++;
        }
        s_isf32 = (hits>=160) ? 0 : 1;
        if (blockIdx.x==0) *flag = s_isf32;
    }
    __syncthreads();
    bool isf32 = s_isf32!=0;
    int stride = gridDim.x*blockDim.x;
    for (int s=0;s<22;s++){
        int n=a.n[s]; const void* sp=a.src[s]; u16* dp=blob+a.off[s];
        for (int i=blockIdx.x*blockDim.x+threadIdx.x; i<n; i+=stride)
            dp[i] = isf32 ? f2b(((const float*)sp)[i]) : ((const u16*)sp)[i];
    }
}

// canonical blob element offsets
#define CX      0
#define CEA     67584
#define CG1WL   67880
#define CG1WR   68904
#define CG1WE   69928
#define CG1ATT  71464
#define CG1B    71976
#define CG2WL   72488
#define CG2WR   334632
#define CG2WE   596776
#define CG2ATT  598312
#define CG2B    598824
#define CL1WIH  599336
#define CL1WHH  9250088
#define CL1BIH  9315624
#define CL1BHH  9316136
#define CL2WIH  9316648
#define CL2WHH  9349416
#define CL2BIH  9365800
#define CL2BHH  9366056
#define CFCW    9366312
#define CFCB    9366568

// ---------------------------------------------------------------------------
// prep (merged setup+wlrt+permw)
// ---------------------------------------------------------------------------
__global__ void prep_kernel(const int* ei, const u16* ea,
                            const u16* g1_we, const u16* g2_we,
                            const u16* g2_wl, const u16* g2_wr,
                            const u16* w1hh, const u16* w2ih, const u16* w2hh,
                            int* csr, float* ep1, float* ep2, u16* wlrt,
                            u16* w1p, u16* w2ip, u16* w2hp)
{
    int b = blockIdx.x, tid = threadIdx.x;
    if (b==0){
        if (tid == 0) {
            int cnt[NN]; for (int n=0;n<NN;n++) cnt[n]=0;
            for (int e=0;e<NE;e++) cnt[ei[NE+e]]++;
            int off=0;
            for (int n=0;n<NN;n++){ csr[n]=off; off+=cnt[n]; }
            csr[NN]=off;
            int pos[NN]; for (int n=0;n<NN;n++) pos[n]=csr[n];
            for (int e=0;e<NE;e++){ int d=ei[NE+e]; csr[34+pos[d]]=e; pos[d]++; }
            for (int e=0;e<NE;e++){ csr[131+e]=ei[e]; csr[228+e]=ei[NE+e]; }
        }
        for (int i=tid; i<NE*512; i+=256) {
            int e = i>>9, hc = i&511;
            float a0=b2f(ea[e*3]), a1=b2f(ea[e*3+1]), a2=b2f(ea[e*3+2]);
            ep1[i] = a0*b2f(g1_we[hc]) + a1*b2f(g1_we[512+hc]) + a2*b2f(g1_we[1024+hc]);
            ep2[i] = a0*b2f(g2_we[hc]) + a1*b2f(g2_we[512+hc]) + a2*b2f(g2_we[1024+hc]);
        }
    } else if (b<=1024){
        int i = (b-1)*256 + tid;
        int k = i>>9, c = i&511;
        wlrt[c*512 + k]        = g2_wl[i];
        wlrt[(c+512)*512 + k]  = g2_wr[i];
    } else {
        int i0 = (b-1025)*256 + tid;
        int stride = 64*256;
        for (int j=i0; j<65536; j+=stride){
            int r=j>>7, k=j&127, u=r>>2, g=r&3;
            w1p[j] = w1hh[(g*128+u)*128 + k];
        }
        for (int j=i0; j<32768; j+=stride){
            int r=j>>7, k=j&127, u=r>>2, g=r&3;
            w2ip[j] = w2ih[(g*64+u)*128 + k];
        }
        for (int j=i0; j<16384; j+=stride){
            int r=j>>6, k=j&63, u=r>>2, g=r&3;
            w2hp[j] = w2hh[(g*64+u)*64 + k];
        }
    }
}

// ---------------------------------------------------------------------------
// GAT layer 1: one block per timestep.
// ---------------------------------------------------------------------------
__global__ __launch_bounds__(256) void gat1_kernel(
    const u16* x, const u16* g1_wl, const u16* g1_wr, const u16* g1_att,
    const u16* g1_b, const float* ep1, const int* csr, u16* h1)
{
    __shared__ float wl[2][512], wr[2][512], att[512], bias[512];
    __shared__ float xt[2*NN];
    __shared__ float logits[NE*8];
    __shared__ float mmax[NN*8], den[NN*8];
    __shared__ int s_off[NN+1], s_eid[NE], s_src[NE], s_dst[NE];
    int t = blockIdx.x, tid = threadIdx.x;

    for (int i=tid;i<512;i+=256){
        wl[0][i]=b2f(g1_wl[i]);      wl[1][i]=b2f(g1_wl[512+i]);
        wr[0][i]=b2f(g1_wr[i]);      wr[1][i]=b2f(g1_wr[512+i]);
        att[i]=b2f(g1_att[i]);       bias[i]=b2f(g1_b[i]);
    }
    for (int i=tid;i<2*NN;i+=256) xt[i]=b2f(x[t*(2*NN)+i]);
    if (tid<NN+1) s_off[tid]=csr[tid];
    for (int i=tid;i<NE;i+=256){ s_eid[i]=csr[34+i]; s_src[i]=csr[131+i]; s_dst[i]=csr[228+i]; }
    __syncthreads();

    for (int i=tid; i<NE*8; i+=256) {
        int e=i>>3, h=i&7;
        int s=s_src[e], d=s_dst[e];
        float xs0=xt[s*2], xs1=xt[s*2+1], xd0=xt[d*2], xd1=xt[d*2+1];
        const float* epp = ep1 + e*512 + h*64;
        float acc=0.f;
        #pragma unroll 8
        for (int c=0;c<64;c++){
            int hc=h*64+c;
            float v = xs0*wl[0][hc] + xs1*wl[1][hc]
                    + xd0*wr[0][hc] + xd1*wr[1][hc] + epp[c];
            v = v>0.f ? v : 0.2f*v;
            acc += att[hc]*v;
        }
        logits[i]=acc;
    }
    __syncthreads();
    for (int i=tid; i<NN*8; i+=256) {
        int n=i>>3, h=i&7;
        float m=-1e30f;
        for (int p=s_off[n]; p<s_off[n+1]; ++p){ float v=logits[s_eid[p]*8+h]; m=v>m?v:m; }
        float s=0.f;
        for (int p=s_off[n]; p<s_off[n+1]; ++p) s += __expf(logits[s_eid[p]*8+h]-m);
        mmax[i]=m; den[i]=s+1e-16f;
    }
    __syncthreads();
    for (int i=tid; i<NE*8; i+=256) {
        int h=i&7, d=s_dst[i>>3];
        logits[i] = __expf(logits[i]-mmax[d*8+h]) / den[d*8+h];
    }
    __syncthreads();
    for (int i=tid; i<NN*512; i+=256) {
        int n=i>>9, hc=i&511, h=hc>>6;
        float acc=0.f;
        for (int p=s_off[n]; p<s_off[n+1]; ++p){
            int e=s_eid[p]; int s=s_src[e];
            float xlv = xt[s*2]*wl[0][hc] + xt[s*2+1]*wl[1][hc];
            acc += logits[e*8+h]*xlv;
        }
        acc += bias[hc];
        acc = acc>0.f ? acc : __expf(acc)-1.f;
        h1[(size_t)(t*NN+n)*512 + hc] = f2b(acc);
    }
}

// ---------------------------------------------------------------------------
// NT GEMM: C[M,N] = A[M,K] * B[N,K]^T, bf16 in, fp32 acc. 128x128 tile.
// Staging via global_load_lds width=16.
// ---------------------------------------------------------------------------
__global__ __launch_bounds__(256) void gemm_nt(
    const u16* __restrict__ A, const u16* __restrict__ B, void* Cout,
    int M, int N, int K, int kChunk, int mode)
{
    __shared__ u16 lds_a[128*32];
    __shared__ u16 lds_b[128*32];
    const int nt = blockIdx.x, mt = blockIdx.y, kc = blockIdx.z;
    const int tid = threadIdx.x;
    const int wave = tid>>6, lane = tid&63;
    const int wm = (wave&1)*64, wn = (wave>>1)*64;
    const int l15 = lane&15, quad = lane>>4;
    const int srow = tid>>2, scol = (tid&3)*8;

    const u16* Ab = A + (size_t)mt*128*K;
    const u16* Bb = B + (size_t)nt*128*K;
    const int k0beg = kc*kChunk, k0end = k0beg + kChunk;

    f32x4 acc[4][4] = {};
    for (int k0 = k0beg; k0 < k0end; k0 += 32) {
        #pragma unroll
        for (int r = 0; r < 2; ++r) {
            int row = srow + r*64;
            const u16* ga = Ab + (size_t)row*K + k0 + scol;
            const u16* gb = Bb + (size_t)row*K + k0 + scol;
            u16* la = &lds_a[(r*64 + wave*16)*32];
            u16* lb = &lds_b[(r*64 + wave*16)*32];
            __builtin_amdgcn_global_load_lds((const u32*)ga, (u32*)la, 16, 0, 0);
            __builtin_amdgcn_global_load_lds((const u32*)gb, (u32*)lb, 16, 0, 0);
        }
        __syncthreads();
        short8 af[4], bfr[4];
        #pragma unroll
        for (int i=0;i<4;i++) af[i]  = *(const short8*)&lds_a[(wm + i*16 + l15)*32 + quad*8];
        #pragma unroll
        for (int j=0;j<4;j++) bfr[j] = *(const short8*)&lds_b[(wn + j*16 + l15)*32 + quad*8];
        #pragma unroll
        for (int i=0;i<4;i++)
            #pragma unroll
            for (int j=0;j<4;j++)
                acc[i][j] = __builtin_amdgcn_mfma_f32_16x16x32_bf16(af[i], bfr[j], acc[i][j], 0,0,0);
        __syncthreads();
    }
    if (mode == 0) {
        u16* Cb = (u16*)Cout;
        #pragma unroll
        for (int i=0;i<4;i++)
            #pragma unroll
            for (int j=0;j<4;j++)
                #pragma unroll
                for (int r=0;r<4;r++){
                    int row = mt*128 + wm + i*16 + quad*4 + r;
                    int col = nt*128 + wn + j*16 + l15;
                    Cb[(size_t)row*N + col] = f2b(acc[i][j][r]);
                }
    } else {
        float* Cb = (float*)Cout + (size_t)kc*M*N;
        #pragma unroll
        for (int i=0;i<4;i++)
            #pragma unroll
            for (int j=0;j<4;j++)
                #pragma unroll
                for (int r=0;r<4;r++){
                    int row = mt*128 + wm + i*16 + quad*4 + r;
                    int col = nt*128 + wn + j*16 + l15;
                    Cb[(size_t)row*N + col] = acc[i][j][r];
                }
    }
}

// reduce 16 split-K partials, permute cols to unit-major (r'=u*4+g), ADD BIAS
__global__ void reduce16_kernel(const float* part, const u16* b1ih, const u16* b1bhh, float* out)
{
    int i = blockIdx.x*256 + threadIdx.x;
    float s=0.f;
    #pragma unroll
    for (int k=0;k<16;k++) s += part[(size_t)k*524288 + i];
    int t=i>>9, c=i&511;
    s += b2f(b1ih[c]) + b2f(b1bhh[c]);
    out[t*512 + ((c&127)<<2) + (c>>7)] = s;
}

// ---------------------------------------------------------------------------
// GAT layer 2 attention; writes h2 PERMUTED [n][t][c].
// ---------------------------------------------------------------------------
__global__ __launch_bounds__(256) void gat2_kernel(
    const u16* C, const u16* g2_att, const u16* g2_b, const float* ep2,
    const int* csr, u16* h2)
{
    __shared__ u16 xl[NN*512];
    __shared__ float att[512], bias[512];
    __shared__ float part[NE*8];
    __shared__ float logit[NE], alpha[NE], mm[NN], dd[NN];
    __shared__ int s_off[NN+1], s_eid[NE], s_src[NE], s_dst[NE];
    int t = blockIdx.x, tid = threadIdx.x;

    for (int i=tid;i<512;i+=256){ att[i]=b2f(g2_att[i]); bias[i]=b2f(g2_b[i]); }
    if (tid<NN+1) s_off[tid]=csr[tid];
    for (int i=tid;i<NE;i+=256){ s_eid[i]=csr[34+i]; s_src[i]=csr[131+i]; s_dst[i]=csr[228+i]; }
    for (int i=tid; i<NN*64; i+=256){
        int n=i>>6, q=i&63;
        *(ushort8*)&xl[n*512+q*8] = *(const ushort8*)&C[(size_t)(t*NN+n)*1024 + q*8];
    }
    __syncthreads();

    for (int i=tid; i<NE*8; i+=256){
        int e=i>>3, q=i&7;
        int s=s_src[e], d=s_dst[e];
        const u16* xrp = C + (size_t)(t*NN+d)*1024 + 512 + q*64;
        const float* epp = ep2 + e*512 + q*64;
        const u16* xlp = xl + s*512 + q*64;
        float acc=0.f;
        #pragma unroll 8
        for (int c=0;c<64;c++){
            float v = b2f(xlp[c]) + b2f(xrp[c]) + epp[c];
            v = v>0.f ? v : 0.2f*v;
            acc += att[q*64+c]*v;
        }
        part[i]=acc;
    }
    __syncthreads();
    for (int i=tid;i<NE;i+=256){
        float s=0.f;
        #pragma unroll
        for (int q=0;q<8;q++) s+=part[i*8+q];
        logit[i]=s;
    }
    __syncthreads();
    for (int i=tid;i<NN;i+=256){
        float m=-1e30f;
        for (int p=s_off[i];p<s_off[i+1];++p){ float v=logit[s_eid[p]]; m=v>m?v:m; }
        float s=0.f;
        for (int p=s_off[i];p<s_off[i+1];++p) s+=__expf(logit[s_eid[p]]-m);
        mm[i]=m; dd[i]=s+1e-16f;
    }
    __syncthreads();
    for (int i=tid;i<NE;i+=256) alpha[i]=__expf(logit[i]-mm[s_dst[i]])/dd[s_dst[i]];
    __syncthreads();
    for (int i=tid;i<NN*512;i+=256){
        int n=i>>9, c=i&511;
        float acc=0.f;
        for (int p=s_off[n];p<s_off[n+1];++p){ int e=s_eid[p]; acc += alpha[e]*b2f(xl[s_src[e]*512+c]); }
        acc += bias[c];
        acc = acc>0.f ? acc : __expf(acc)-1.f;
        h2[(size_t)n*524288 + (size_t)t*512 + c] = f2b(acc);
    }
}

// ---------------------------------------------------------------------------
// FUSED LSTM v6: 2-block pipeline at 256 threads/block (4 waves).
//  Producer: 4 waves x 8 tiles (128 rows each) = same 128 MFMA/step issue,
//  but half the barrier arrivals and half the redundant LDS B-reads.
//  Consumer rescaled to 4 waves (tiles x2). Protocol unchanged.
// ---------------------------------------------------------------------------
__global__ __launch_bounds__(256) void lstm_fused_kernel(
    const float* __restrict__ pre1p,
    const u16* __restrict__ w1p,
    const u16* __restrict__ w2ip, const u16* __restrict__ w2hp,
    const u16* b2ih, const u16* b2bhh,
    const u16* fc_w, const u16* fc_b, const int* flag,
    u32* ring, u32* flags, void* outv)
{
    const int tid = threadIdx.x;
    const int wave = tid>>6, lane = tid&63;
    const int l15 = lane&15, quad = lane>>4;
    const f32x4 fz = {0.f,0.f,0.f,0.f};

    if (blockIdx.x == 0) {
        // ================= producer: lstm1 (4 waves x 128 rows) =============
        __shared__ __align__(16) float pre_c[32*512];   // 64 KB
        __shared__ __align__(16) float z_lds[512];      // unit-major z
        __shared__ __align__(16) u16 hb1[2][128];
        __shared__ __align__(16) u16 hchunk[16*128];    // 4 KB
        const float4* p4g = (const float4*)pre1p;
        float4* c4 = (float4*)pre_c;
        u32* hc32 = (u32*)hchunk;

        short8 af1[8][4];
        #pragma unroll
        for (int i=0;i<8;i++)
            #pragma unroll
            for (int c=0;c<4;c++)
                af1[i][c] = *(const short8*)&w1p[(size_t)(wave*128 + i*16 + l15)*128 + c*32 + quad*8];

        float cst = 0.f;
        if (tid<128) hb1[1][tid]=0;

        const u16* hqA = &hb1[1][quad*8];   // read when k even
        const u16* hqB = &hb1[0][quad*8];
        const float* pcp = pre_c;
        float* zst = &z_lds[wave*128 + quad*4];   // store base (l15==0 lanes)

        for (int k=0;k<=1024;k++){
            if (k>=16 && (k&15)==0){
                int c = (k>>4) - 1;
                u32* dst = ring + c*1024;
                #pragma unroll
                for (int j=0;j<4;j++)
                    __hip_atomic_store(&dst[tid + j*256], hc32[tid + j*256],
                                       __ATOMIC_RELAXED, __HIP_MEMORY_SCOPE_AGENT);
                __syncthreads();
                if (tid==0)
                    __hip_atomic_store(&flags[c], (u32)(c+1), __ATOMIC_RELEASE, __HIP_MEMORY_SCOPE_AGENT);
            }
            if (k<1024 && (k&31)==0){
                #pragma unroll
                for (int j=0;j<16;j++) c4[j*256+tid] = p4g[(size_t)k*128 + j*256 + tid];
                pcp = pre_c;
                __syncthreads();
            }
            if (k<1024){
                const u16* hq = (k&1) ? hqB : hqA;
                short8 b0 = *(const short8*)&hq[0];
                short8 b1 = *(const short8*)&hq[32];
                short8 b2 = *(const short8*)&hq[64];
                short8 b3 = *(const short8*)&hq[96];
                f32x4 acc[8];
                #pragma unroll
                for (int i=0;i<8;i++){
                    f32x4 a = __builtin_amdgcn_mfma_f32_16x16x32_bf16(af1[i][0], b0, fz, 0,0,0);
                    a = __builtin_amdgcn_mfma_f32_16x16x32_bf16(af1[i][1], b1, a, 0,0,0);
                    a = __builtin_amdgcn_mfma_f32_16x16x32_bf16(af1[i][2], b2, a, 0,0,0);
                    a = __builtin_amdgcn_mfma_f32_16x16x32_bf16(af1[i][3], b3, a, 0,0,0);
                    acc[i] = a;
                }
                if (l15==0){
                    #pragma unroll
                    for (int i=0;i<8;i++)
                        *(f32x4*)&zst[i*16] = acc[i];
                }
                __syncthreads();
                if (tid<128){
                    f32x4 z = *(const f32x4*)&z_lds[tid*4];
                    const float4 pf = *(const float4*)&pcp[tid*4];   // bias folded
                    float zi = z[0]+pf.x;
                    float zf = z[1]+pf.y;
                    float zg = z[2]+pf.z;
                    float zo = z[3]+pf.w;
                    cst = sigm(zf)*cst + sigm(zi)*tanh_(zg);
                    float ho = sigm(zo)*tanh_(cst);
                    u16 hv = f2b(ho);
                    hb1[k&1][tid] = hv;
                    hchunk[(k&15)*128 + tid] = hv;
                }
                pcp += 512;
            }
            __syncthreads();
        }
    } else {
        // ================= consumer: lstm2 + FC (4 waves) ===================
        __shared__ __align__(16) u16 h1c[16*136];
        __shared__ __align__(16) float z2l[16*264];
        __shared__ __align__(16) u16 hb2[2][64];
        __shared__ float hf[64];

        short8 af2[4][2];
        #pragma unroll
        for (int j=0;j<4;j++)
            #pragma unroll
            for (int c=0;c<2;c++)
                af2[j][c] = *(const short8*)&w2hp[(size_t)(wave*64 + j*16 + l15)*64 + c*32 + quad*8];
        short8 af3[4][4];
        #pragma unroll
        for (int j=0;j<4;j++)
            #pragma unroll
            for (int c=0;c<4;c++)
                af3[j][c] = *(const short8*)&w2ip[(size_t)(wave*64 + j*16 + l15)*128 + c*32 + quad*8];

        int u2 = 0; float bz0=0,bz1=0,bz2=0,bz3=0;
        if (l15<4){
            u2 = wave*16 + l15*4 + quad;
            bz0 = b2f(b2ih[u2])     + b2f(b2bhh[u2]);
            bz1 = b2f(b2ih[64+u2])  + b2f(b2bhh[64+u2]);
            bz2 = b2f(b2ih[128+u2]) + b2f(b2bhh[128+u2]);
            bz3 = b2f(b2ih[192+u2]) + b2f(b2bhh[192+u2]);
        }
        float cst = 0.f;
        if (tid<64) hb2[1][tid]=0;
        __syncthreads();

        u32* h1c32 = (u32*)h1c;
        for (int c=0;c<64;c++){
            if (tid==0){
                while (__hip_atomic_load(&flags[c], __ATOMIC_ACQUIRE, __HIP_MEMORY_SCOPE_AGENT) != (u32)(c+1))
                    __builtin_amdgcn_s_sleep(2);
            }
            __syncthreads();
            const u32* src = ring + c*1024;
            #pragma unroll
            for (int j=0;j<4;j++){
                int i = tid + j*256;
                u32 v = __hip_atomic_load(&src[i], __ATOMIC_RELAXED, __HIP_MEMORY_SCOPE_AGENT);
                int s = i>>6, w2 = i&63;
                h1c32[s*68 + w2] = v;
            }
            __syncthreads();
            short8 hbv[4];
            #pragma unroll
            for (int cc=0;cc<4;cc++)
                hbv[cc] = *(const short8*)&h1c[l15*136 + cc*32 + quad*8];
            f32x4 ba[4] = {fz,fz,fz,fz};
            #pragma unroll
            for (int cc=0;cc<4;cc++)
                #pragma unroll
                for (int j=0;j<4;j++)
                    ba[j] = __builtin_amdgcn_mfma_f32_16x16x32_bf16(af3[j][cc], hbv[cc], ba[j], 0,0,0);
            #pragma unroll
            for (int j=0;j<4;j++)
                *(f32x4*)&z2l[l15*264 + (wave*16 + j*4 + quad)*4] = ba[j];
            __syncthreads();
            for (int s=0;s<16;s++){
                int sg = c*16 + s;
                const u16* hp2 = hb2[(sg+1)&1];
                short8 g0 = *(const short8*)&hp2[quad*8];
                short8 g1 = *(const short8*)&hp2[32+quad*8];
                f32x4 a[4];
                #pragma unroll
                for (int j=0;j<4;j++){
                    f32x4 t0 = __builtin_amdgcn_mfma_f32_16x16x32_bf16(af2[j][0], g0, fz, 0,0,0);
                    a[j] = __builtin_amdgcn_mfma_f32_16x16x32_bf16(af2[j][1], g1, t0, 0,0,0);
                }
                f32x4 z = a[0];
                #pragma unroll
                for (int j=1;j<4;j++) z = (l15==j) ? a[j] : z;
                if (l15<4){
                    const float4 pf = *(const float4*)&z2l[s*264 + u2*4];
                    float zi = z[0]+pf.x+bz0;
                    float zf = z[1]+pf.y+bz1;
                    float zg = z[2]+pf.z+bz2;
                    float zo = z[3]+pf.w+bz3;
                    cst = sigm(zf)*cst + sigm(zi)*tanh_(zg);
                    float ho = sigm(zo)*tanh_(cst);
                    hb2[sg&1][u2] = f2b(ho);
                    hf[u2] = ho;
                }
                __syncthreads();
            }
        }
        if (tid<4){
            float acc = b2f(fc_b[tid]);
            #pragma unroll
            for (int j=0;j<64;j++) acc += hf[j]*b2f(fc_w[tid*64+j]);
            if (*flag) ((float*)outv)[tid] = acc;
            else       ((u16*)outv)[tid]  = f2b(acc);
        }
    }
}

// ---------------------------------------------------------------------------
extern "C" void kernel_launch(void* const* d_in, const int* in_sizes, int n_in,
                              void* d_out, int out_size, void* d_ws, size_t ws_size,
                              hipStream_t stream) {
    const int* ei = (const int*)d_in[1];
    char* ws = (char*)d_ws;

    const size_t o_blob = 0;
    const size_t o_h    = 18733184;
    const size_t o_C    = o_h    + 34603008;
    const size_t o_wlrt = o_C    + 69206016;
    const size_t o_ep1  = o_wlrt + 1048576;
    const size_t o_ep2  = o_ep1  + 198656;
    const size_t o_csr  = o_ep2  + 198656;
    const size_t o_pre1 = o_csr  + 2048;
    const size_t o_w1p  = o_pre1 + 2097152;
    const size_t o_w2ip = o_w1p  + 131072;
    const size_t o_w2hp = o_w2ip + 65536;
    const size_t o_ring = o_w2hp + 32768;
    const size_t o_flgs = o_ring + 262144;

    u16*   blob  = (u16*)(ws + o_blob);
    u16*   h_buf = (u16*)(ws + o_h);
    u16*   Cbuf  = (u16*)(ws + o_C);
    u16*   wlrt  = (u16*)(ws + o_wlrt);
    float* ep1   = (float*)(ws + o_ep1);
    float* ep2   = (float*)(ws + o_ep2);
    int*   csr   = (int*)(ws + o_csr);
    int*   flag  = csr + 400;
    float* pre1  = (float*)(ws + o_pre1);
    u16*   w1p   = (u16*)(ws + o_w1p);
    u16*   w2ip  = (u16*)(ws + o_w2ip);
    u16*   w2hp  = (u16*)(ws + o_w2hp);
    u32*   ring  = (u32*)(ws + o_ring);
    u32*   flags = (u32*)(ws + o_flgs);
    float* part  = (float*)(ws + o_C);

    ConvArgs ca;
    const int blob_off[22] = {CX,CEA,CG1WL,CG1WR,CG1WE,CG1ATT,CG1B,
                              CG2WL,CG2WR,CG2WE,CG2ATT,CG2B,
                              CL1WIH,CL1WHH,CL1BIH,CL1BHH,
                              CL2WIH,CL2WHH,CL2BIH,CL2BHH,CFCW,CFCB};
    const int in_idx[22]   = {0,2,3,4,5,6,7,8,9,10,11,12,13,14,15,16,17,18,19,20,21,22};
    for (int s=0;s<22;s++){
        ca.src[s]=d_in[in_idx[s]]; ca.n[s]=in_sizes[in_idx[s]]; ca.off[s]=blob_off[s];
    }
    convert_kernel<<<2048,256,0,stream>>>(ca, (const u32*)d_in[3], flag, blob);

    prep_kernel<<<1089,256,0,stream>>>(ei, blob+CEA, blob+CG1WE, blob+CG2WE,
                                       blob+CG2WL, blob+CG2WR,
                                       blob+CL1WHH, blob+CL2WIH, blob+CL2WHH,
                                       csr, ep1, ep2, wlrt, w1p, w2ip, w2hp);
    gat1_kernel<<<NT,256,0,stream>>>(blob+CX, blob+CG1WL, blob+CG1WR, blob+CG1ATT,
                                     blob+CG1B, ep1, csr, h_buf);
    gemm_nt<<<dim3(8,264,1),256,0,stream>>>(h_buf, wlrt, Cbuf, 33792, 1024, 512, 512, 0);
    gat2_kernel<<<NT,256,0,stream>>>(Cbuf, blob+CG2ATT, blob+CG2B, ep2, csr, h_buf);
    gemm_nt<<<dim3(4,8,16),256,0,stream>>>(h_buf, blob+CL1WIH, part, 1024, 512, 16896, 1056, 1);
    reduce16_kernel<<<2048,256,0,stream>>>(part, blob+CL1BIH, blob+CL1BHH, pre1);
    lstm_fused_kernel<<<2,256,0,stream>>>(pre1,
        w1p, w2ip, w2hp, blob+CL2BIH, blob+CL2BHH,
        blob+CFCW, blob+CFCB, flag, ring, flags, d_out);
}

// Round 15
// 1326.203 us; speedup vs baseline: 1.0553x; 1.0553x over previous
//
#include <hip/hip_runtime.h>

typedef unsigned short u16;
typedef unsigned int   u32;
typedef __attribute__((ext_vector_type(8))) short  short8;
typedef __attribute__((ext_vector_type(8))) unsigned short ushort8;
typedef __attribute__((ext_vector_type(4))) float  f32x4;

#define NT 1024      // timesteps
#define NN 33        // nodes
#define NE 97        // edges

__device__ __forceinline__ float b2f(u16 u){ return __uint_as_float(((u32)u)<<16); }
__device__ __forceinline__ u16 f2b(float f){
    u32 x = __float_as_uint(f);
    return (u16)((x + 0x7fffu + ((x>>16)&1u)) >> 16);
}
__device__ __forceinline__ float sigm(float x){ return 1.f/(1.f+__expf(-x)); }
__device__ __forceinline__ float tanh_(float x){ float e=__expf(2.f*x); return 1.f - 2.f/(e+1.f); }

// ---------------------------------------------------------------------------
// convert: per-block dtype detection; block 0 publishes flag (0=bf16, 1=fp32).
// ---------------------------------------------------------------------------
struct ConvArgs { const void* src[22]; int n[22]; int off[22]; };
__global__ void convert_kernel(ConvArgs a, const u32* raw, int* flag, u16* blob){
    __shared__ int s_isf32;
    if (threadIdx.x==0){
        int hits=0;
        for (int k=0;k<256;k++){
            u32 w = raw[k];
            u32 e = (w>>7)&0xffu;
            if (e>=96u && e<=126u) hits++;
        }
        s_isf32 = (hits>=160) ? 0 : 1;
        if (blockIdx.x==0) *flag = s_isf32;
    }
    __syncthreads();
    bool isf32 = s_isf32!=0;
    int stride = gridDim.x*blockDim.x;
    for (int s=0;s<22;s++){
        int n=a.n[s]; const void* sp=a.src[s]; u16* dp=blob+a.off[s];
        for (int i=blockIdx.x*blockDim.x+threadIdx.x; i<n; i+=stride)
            dp[i] = isf32 ? f2b(((const float*)sp)[i]) : ((const u16*)sp)[i];
    }
}

// canonical blob element offsets
#define CX      0
#define CEA     67584
#define CG1WL   67880
#define CG1WR   68904
#define CG1WE   69928
#define CG1ATT  71464
#define CG1B    71976
#define CG2WL   72488
#define CG2WR   334632
#define CG2WE   596776
#define CG2ATT  598312
#define CG2B    598824
#define CL1WIH  599336
#define CL1WHH  9250088
#define CL1BIH  9315624
#define CL1BHH  9316136
#define CL2WIH  9316648
#define CL2WHH  9349416
#define CL2BIH  9365800
#define CL2BHH  9366056
#define CFCW    9366312
#define CFCB    9366568

// ---------------------------------------------------------------------------
// prep (merged setup+wlrt+permw)
// ---------------------------------------------------------------------------
__global__ void prep_kernel(const int* ei, const u16* ea,
                            const u16* g1_we, const u16* g2_we,
                            const u16* g2_wl, const u16* g2_wr,
                            const u16* w1hh, const u16* w2ih, const u16* w2hh,
                            int* csr, float* ep1, float* ep2, u16* wlrt,
                            u16* w1p, u16* w2ip, u16* w2hp)
{
    int b = blockIdx.x, tid = threadIdx.x;
    if (b==0){
        if (tid == 0) {
            int cnt[NN]; for (int n=0;n<NN;n++) cnt[n]=0;
            for (int e=0;e<NE;e++) cnt[ei[NE+e]]++;
            int off=0;
            for (int n=0;n<NN;n++){ csr[n]=off; off+=cnt[n]; }
            csr[NN]=off;
            int pos[NN]; for (int n=0;n<NN;n++) pos[n]=csr[n];
            for (int e=0;e<NE;e++){ int d=ei[NE+e]; csr[34+pos[d]]=e; pos[d]++; }
            for (int e=0;e<NE;e++){ csr[131+e]=ei[e]; csr[228+e]=ei[NE+e]; }
        }
        for (int i=tid; i<NE*512; i+=256) {
            int e = i>>9, hc = i&511;
            float a0=b2f(ea[e*3]), a1=b2f(ea[e*3+1]), a2=b2f(ea[e*3+2]);
            ep1[i] = a0*b2f(g1_we[hc]) + a1*b2f(g1_we[512+hc]) + a2*b2f(g1_we[1024+hc]);
            ep2[i] = a0*b2f(g2_we[hc]) + a1*b2f(g2_we[512+hc]) + a2*b2f(g2_we[1024+hc]);
        }
    } else if (b<=1024){
        int i = (b-1)*256 + tid;
        int k = i>>9, c = i&511;
        wlrt[c*512 + k]        = g2_wl[i];
        wlrt[(c+512)*512 + k]  = g2_wr[i];
    } else {
        int i0 = (b-1025)*256 + tid;
        int stride = 64*256;
        for (int j=i0; j<65536; j+=stride){
            int r=j>>7, k=j&127, u=r>>2, g=r&3;
            w1p[j] = w1hh[(g*128+u)*128 + k];
        }
        for (int j=i0; j<32768; j+=stride){
            int r=j>>7, k=j&127, u=r>>2, g=r&3;
            w2ip[j] = w2ih[(g*64+u)*128 + k];
        }
        for (int j=i0; j<16384; j+=stride){
            int r=j>>6, k=j&63, u=r>>2, g=r&3;
            w2hp[j] = w2hh[(g*64+u)*64 + k];
        }
    }
}

// ---------------------------------------------------------------------------
// GAT layer 1: one block per timestep.
// ---------------------------------------------------------------------------
__global__ __launch_bounds__(256) void gat1_kernel(
    const u16* x, const u16* g1_wl, const u16* g1_wr, const u16* g1_att,
    const u16* g1_b, const float* ep1, const int* csr, u16* h1)
{
    __shared__ float wl[2][512], wr[2][512], att[512], bias[512];
    __shared__ float xt[2*NN];
    __shared__ float logits[NE*8];
    __shared__ float mmax[NN*8], den[NN*8];
    __shared__ int s_off[NN+1], s_eid[NE], s_src[NE], s_dst[NE];
    int t = blockIdx.x, tid = threadIdx.x;

    for (int i=tid;i<512;i+=256){
        wl[0][i]=b2f(g1_wl[i]);      wl[1][i]=b2f(g1_wl[512+i]);
        wr[0][i]=b2f(g1_wr[i]);      wr[1][i]=b2f(g1_wr[512+i]);
        att[i]=b2f(g1_att[i]);       bias[i]=b2f(g1_b[i]);
    }
    for (int i=tid;i<2*NN;i+=256) xt[i]=b2f(x[t*(2*NN)+i]);
    if (tid<NN+1) s_off[tid]=csr[tid];
    for (int i=tid;i<NE;i+=256){ s_eid[i]=csr[34+i]; s_src[i]=csr[131+i]; s_dst[i]=csr[228+i]; }
    __syncthreads();

    for (int i=tid; i<NE*8; i+=256) {
        int e=i>>3, h=i&7;
        int s=s_src[e], d=s_dst[e];
        float xs0=xt[s*2], xs1=xt[s*2+1], xd0=xt[d*2], xd1=xt[d*2+1];
        const float* epp = ep1 + e*512 + h*64;
        float acc=0.f;
        #pragma unroll 8
        for (int c=0;c<64;c++){
            int hc=h*64+c;
            float v = xs0*wl[0][hc] + xs1*wl[1][hc]
                    + xd0*wr[0][hc] + xd1*wr[1][hc] + epp[c];
            v = v>0.f ? v : 0.2f*v;
            acc += att[hc]*v;
        }
        logits[i]=acc;
    }
    __syncthreads();
    for (int i=tid; i<NN*8; i+=256) {
        int n=i>>3, h=i&7;
        float m=-1e30f;
        for (int p=s_off[n]; p<s_off[n+1]; ++p){ float v=logits[s_eid[p]*8+h]; m=v>m?v:m; }
        float s=0.f;
        for (int p=s_off[n]; p<s_off[n+1]; ++p) s += __expf(logits[s_eid[p]*8+h]-m);
        mmax[i]=m; den[i]=s+1e-16f;
    }
    __syncthreads();
    for (int i=tid; i<NE*8; i+=256) {
        int h=i&7, d=s_dst[i>>3];
        logits[i] = __expf(logits[i]-mmax[d*8+h]) / den[d*8+h];
    }
    __syncthreads();
    for (int i=tid; i<NN*512; i+=256) {
        int n=i>>9, hc=i&511, h=hc>>6;
        float acc=0.f;
        for (int p=s_off[n]; p<s_off[n+1]; ++p){
            int e=s_eid[p]; int s=s_src[e];
            float xlv = xt[s*2]*wl[0][hc] + xt[s*2+1]*wl[1][hc];
            acc += logits[e*8+h]*xlv;
        }
        acc += bias[hc];
        acc = acc>0.f ? acc : __expf(acc)-1.f;
        h1[(size_t)(t*NN+n)*512 + hc] = f2b(acc);
    }
}

// ---------------------------------------------------------------------------
// NT GEMM: C[M,N] = A[M,K] * B[N,K]^T, bf16 in, fp32 acc. 128x128 tile.
// Staging via global_load_lds width=16.
// ---------------------------------------------------------------------------
__global__ __launch_bounds__(256) void gemm_nt(
    const u16* __restrict__ A, const u16* __restrict__ B, void* Cout,
    int M, int N, int K, int kChunk, int mode)
{
    __shared__ u16 lds_a[128*32];
    __shared__ u16 lds_b[128*32];
    const int nt = blockIdx.x, mt = blockIdx.y, kc = blockIdx.z;
    const int tid = threadIdx.x;
    const int wave = tid>>6, lane = tid&63;
    const int wm = (wave&1)*64, wn = (wave>>1)*64;
    const int l15 = lane&15, quad = lane>>4;
    const int srow = tid>>2, scol = (tid&3)*8;

    const u16* Ab = A + (size_t)mt*128*K;
    const u16* Bb = B + (size_t)nt*128*K;
    const int k0beg = kc*kChunk, k0end = k0beg + kChunk;

    f32x4 acc[4][4] = {};
    for (int k0 = k0beg; k0 < k0end; k0 += 32) {
        #pragma unroll
        for (int r = 0; r < 2; ++r) {
            int row = srow + r*64;
            const u16* ga = Ab + (size_t)row*K + k0 + scol;
            const u16* gb = Bb + (size_t)row*K + k0 + scol;
            u16* la = &lds_a[(r*64 + wave*16)*32];
            u16* lb = &lds_b[(r*64 + wave*16)*32];
            __builtin_amdgcn_global_load_lds((const u32*)ga, (u32*)la, 16, 0, 0);
            __builtin_amdgcn_global_load_lds((const u32*)gb, (u32*)lb, 16, 0, 0);
        }
        __syncthreads();
        short8 af[4], bfr[4];
        #pragma unroll
        for (int i=0;i<4;i++) af[i]  = *(const short8*)&lds_a[(wm + i*16 + l15)*32 + quad*8];
        #pragma unroll
        for (int j=0;j<4;j++) bfr[j] = *(const short8*)&lds_b[(wn + j*16 + l15)*32 + quad*8];
        #pragma unroll
        for (int i=0;i<4;i++)
            #pragma unroll
            for (int j=0;j<4;j++)
                acc[i][j] = __builtin_amdgcn_mfma_f32_16x16x32_bf16(af[i], bfr[j], acc[i][j], 0,0,0);
        __syncthreads();
    }
    if (mode == 0) {
        u16* Cb = (u16*)Cout;
        #pragma unroll
        for (int i=0;i<4;i++)
            #pragma unroll
            for (int j=0;j<4;j++)
                #pragma unroll
                for (int r=0;r<4;r++){
                    int row = mt*128 + wm + i*16 + quad*4 + r;
                    int col = nt*128 + wn + j*16 + l15;
                    Cb[(size_t)row*N + col] = f2b(acc[i][j][r]);
                }
    } else {
        float* Cb = (float*)Cout + (size_t)kc*M*N;
        #pragma unroll
        for (int i=0;i<4;i++)
            #pragma unroll
            for (int j=0;j<4;j++)
                #pragma unroll
                for (int r=0;r<4;r++){
                    int row = mt*128 + wm + i*16 + quad*4 + r;
                    int col = nt*128 + wn + j*16 + l15;
                    Cb[(size_t)row*N + col] = acc[i][j][r];
                }
    }
}

// reduce 16 split-K partials, permute cols to unit-major (r'=u*4+g), ADD BIAS
__global__ void reduce16_kernel(const float* part, const u16* b1ih, const u16* b1bhh, float* out)
{
    int i = blockIdx.x*256 + threadIdx.x;
    float s=0.f;
    #pragma unroll
    for (int k=0;k<16;k++) s += part[(size_t)k*524288 + i];
    int t=i>>9, c=i&511;
    s += b2f(b1ih[c]) + b2f(b1bhh[c]);
    out[t*512 + ((c&127)<<2) + (c>>7)] = s;
}

// ---------------------------------------------------------------------------
// GAT layer 2 attention; writes h2 PERMUTED [n][t][c].
// ---------------------------------------------------------------------------
__global__ __launch_bounds__(256) void gat2_kernel(
    const u16* C, const u16* g2_att, const u16* g2_b, const float* ep2,
    const int* csr, u16* h2)
{
    __shared__ u16 xl[NN*512];
    __shared__ float att[512], bias[512];
    __shared__ float part[NE*8];
    __shared__ float logit[NE], alpha[NE], mm[NN], dd[NN];
    __shared__ int s_off[NN+1], s_eid[NE], s_src[NE], s_dst[NE];
    int t = blockIdx.x, tid = threadIdx.x;

    for (int i=tid;i<512;i+=256){ att[i]=b2f(g2_att[i]); bias[i]=b2f(g2_b[i]); }
    if (tid<NN+1) s_off[tid]=csr[tid];
    for (int i=tid;i<NE;i+=256){ s_eid[i]=csr[34+i]; s_src[i]=csr[131+i]; s_dst[i]=csr[228+i]; }
    for (int i=tid; i<NN*64; i+=256){
        int n=i>>6, q=i&63;
        *(ushort8*)&xl[n*512+q*8] = *(const ushort8*)&C[(size_t)(t*NN+n)*1024 + q*8];
    }
    __syncthreads();

    for (int i=tid; i<NE*8; i+=256){
        int e=i>>3, q=i&7;
        int s=s_src[e], d=s_dst[e];
        const u16* xrp = C + (size_t)(t*NN+d)*1024 + 512 + q*64;
        const float* epp = ep2 + e*512 + q*64;
        const u16* xlp = xl + s*512 + q*64;
        float acc=0.f;
        #pragma unroll 8
        for (int c=0;c<64;c++){
            float v = b2f(xlp[c]) + b2f(xrp[c]) + epp[c];
            v = v>0.f ? v : 0.2f*v;
            acc += att[q*64+c]*v;
        }
        part[i]=acc;
    }
    __syncthreads();
    for (int i=tid;i<NE;i+=256){
        float s=0.f;
        #pragma unroll
        for (int q=0;q<8;q++) s+=part[i*8+q];
        logit[i]=s;
    }
    __syncthreads();
    for (int i=tid;i<NN;i+=256){
        float m=-1e30f;
        for (int p=s_off[i];p<s_off[i+1];++p){ float v=logit[s_eid[p]]; m=v>m?v:m; }
        float s=0.f;
        for (int p=s_off[i];p<s_off[i+1];++p) s+=__expf(logit[s_eid[p]]-m);
        mm[i]=m; dd[i]=s+1e-16f;
    }
    __syncthreads();
    for (int i=tid;i<NE;i+=256) alpha[i]=__expf(logit[i]-mm[s_dst[i]])/dd[s_dst[i]];
    __syncthreads();
    for (int i=tid;i<NN*512;i+=256){
        int n=i>>9, c=i&511;
        float acc=0.f;
        for (int p=s_off[n];p<s_off[n+1];++p){ int e=s_eid[p]; acc += alpha[e]*b2f(xl[s_src[e]*512+c]); }
        acc += bias[c];
        acc = acc>0.f ? acc : __expf(acc)-1.f;
        h2[(size_t)n*524288 + (size_t)t*512 + c] = f2b(acc);
    }
}

// ---------------------------------------------------------------------------
// FUSED LSTM v7: 2-block pipeline, 512 thr. Producer: SINGLE barrier/step.
//  Key fact: h B-fragment loads are wave-uniform -> every B column holds h ->
//  every lane's acc[i][0..3] = z rows i*16+quad*4+{0..3} (l15-independent).
//  With unit-major weight rows, acc[i] = full gate set of unit
//  u = wave*16 + i*4 + quad. Blend z=acc[l15] (l15<4), gates in registers,
//  masked b16 writes of h. No z LDS round-trip, ONE barrier per step.
// ---------------------------------------------------------------------------
__global__ __launch_bounds__(512) void lstm_fused_kernel(
    const float* __restrict__ pre1p,
    const u16* __restrict__ w1p,
    const u16* __restrict__ w2ip, const u16* __restrict__ w2hp,
    const u16* b2ih, const u16* b2bhh,
    const u16* fc_w, const u16* fc_b, const int* flag,
    u32* ring, u32* flags, void* outv)
{
    const int tid = threadIdx.x;
    const int wave = tid>>6, lane = tid&63;
    const int l15 = lane&15, quad = lane>>4;
    const f32x4 fz = {0.f,0.f,0.f,0.f};

    if (blockIdx.x == 0) {
        // ================= producer: lstm1, 1 barrier/step =================
        __shared__ __align__(16) float pre_c[32*512];   // 64 KB
        __shared__ __align__(16) u16 hb1[2][128];
        __shared__ __align__(16) u16 hchunk[16*128];    // 4 KB
        const float4* p4g = (const float4*)pre1p;
        float4* c4 = (float4*)pre_c;
        u32* hc32 = (u32*)hchunk;

        short8 af1[4][4];
        #pragma unroll
        for (int i=0;i<4;i++)
            #pragma unroll
            for (int c=0;c<4;c++)
                af1[i][c] = *(const short8*)&w1p[(size_t)(wave*64 + i*16 + l15)*128 + c*32 + quad*8];

        const int uu = wave*16 + ((l15<4)?l15:0)*4 + quad;   // valid l15<4
        float cst = 0.f;
        if (tid<128) hb1[0][tid]=0;

        const u16* hqA = &hb1[0][quad*8];   // read when k even
        const u16* hqB = &hb1[1][quad*8];   // read when k odd
        const float* pcp = pre_c;

        for (int k=0;k<=1024;k++){
            if (k>=16 && (k&15)==0){
                int c = (k>>4) - 1;
                u32* dst = ring + c*1024;
                __hip_atomic_store(&dst[tid],     hc32[tid],     __ATOMIC_RELAXED, __HIP_MEMORY_SCOPE_AGENT);
                __hip_atomic_store(&dst[tid+512], hc32[tid+512], __ATOMIC_RELAXED, __HIP_MEMORY_SCOPE_AGENT);
                __syncthreads();
                if (tid==0)
                    __hip_atomic_store(&flags[c], (u32)(c+1), __ATOMIC_RELEASE, __HIP_MEMORY_SCOPE_AGENT);
            }
            if (k<1024 && (k&31)==0){
                #pragma unroll
                for (int j=0;j<8;j++) c4[j*512+tid] = p4g[(size_t)k*128 + j*512 + tid];
                pcp = pre_c;
                __syncthreads();
            }
            if (k<1024){
                const u16* hq = (k&1) ? hqB : hqA;
                short8 b0 = *(const short8*)&hq[0];
                short8 b1 = *(const short8*)&hq[32];
                short8 b2 = *(const short8*)&hq[64];
                short8 b3 = *(const short8*)&hq[96];
                f32x4 acc[4];
                #pragma unroll
                for (int i=0;i<4;i++){
                    f32x4 a = __builtin_amdgcn_mfma_f32_16x16x32_bf16(af1[i][0], b0, fz, 0,0,0);
                    a = __builtin_amdgcn_mfma_f32_16x16x32_bf16(af1[i][1], b1, a, 0,0,0);
                    a = __builtin_amdgcn_mfma_f32_16x16x32_bf16(af1[i][2], b2, a, 0,0,0);
                    a = __builtin_amdgcn_mfma_f32_16x16x32_bf16(af1[i][3], b3, a, 0,0,0);
                    acc[i] = a;
                }
                // z for unit uu sits in acc[l15] (any column) — blend + gates
                f32x4 z = acc[0];
                z = (l15==1) ? acc[1] : z;
                z = (l15==2) ? acc[2] : z;
                z = (l15==3) ? acc[3] : z;
                if (l15<4){
                    const float4 pf = *(const float4*)&pcp[uu*4];   // bias folded
                    float zi = z[0]+pf.x;
                    float zf = z[1]+pf.y;
                    float zg = z[2]+pf.z;
                    float zo = z[3]+pf.w;
                    cst = sigm(zf)*cst + sigm(zi)*tanh_(zg);
                    float ho = sigm(zo)*tanh_(cst);
                    u16 hv = f2b(ho);
                    hb1[(k+1)&1][uu] = hv;
                    hchunk[(k&15)*128 + uu] = hv;
                }
                pcp += 512;
            }
            __syncthreads();
        }
    } else {
        // ================= consumer: lstm2 + FC (8 waves) ===================
        __shared__ __align__(16) u16 h1c[16*136];
        __shared__ __align__(16) float z2l[16*264];
        __shared__ __align__(16) u16 hb2[2][64];
        __shared__ float hf[64];

        short8 af2[2][2];
        #pragma unroll
        for (int j=0;j<2;j++)
            #pragma unroll
            for (int c=0;c<2;c++)
                af2[j][c] = *(const short8*)&w2hp[(size_t)(wave*32 + j*16 + l15)*64 + c*32 + quad*8];
        short8 af3[2][4];
        #pragma unroll
        for (int j=0;j<2;j++)
            #pragma unroll
            for (int c=0;c<4;c++)
                af3[j][c] = *(const short8*)&w2ip[(size_t)(wave*32 + j*16 + l15)*128 + c*32 + quad*8];

        int u2 = 0; float bz0=0,bz1=0,bz2=0,bz3=0;
        if (l15<2){
            u2 = wave*8 + l15*4 + quad;
            bz0 = b2f(b2ih[u2])     + b2f(b2bhh[u2]);
            bz1 = b2f(b2ih[64+u2])  + b2f(b2bhh[64+u2]);
            bz2 = b2f(b2ih[128+u2]) + b2f(b2bhh[128+u2]);
            bz3 = b2f(b2ih[192+u2]) + b2f(b2bhh[192+u2]);
        }
        float cst = 0.f;
        if (tid<64) hb2[1][tid]=0;
        __syncthreads();

        u32* h1c32 = (u32*)h1c;
        for (int c=0;c<64;c++){
            if (tid==0){
                while (__hip_atomic_load(&flags[c], __ATOMIC_ACQUIRE, __HIP_MEMORY_SCOPE_AGENT) != (u32)(c+1))
                    __builtin_amdgcn_s_sleep(2);
            }
            __syncthreads();
            const u32* src = ring + c*1024;
            #pragma unroll
            for (int j=0;j<2;j++){
                int i = tid + j*512;
                u32 v = __hip_atomic_load(&src[i], __ATOMIC_RELAXED, __HIP_MEMORY_SCOPE_AGENT);
                int s = i>>6, w2 = i&63;
                h1c32[s*68 + w2] = v;
            }
            __syncthreads();
            short8 hbv[4];
            #pragma unroll
            for (int cc=0;cc<4;cc++)
                hbv[cc] = *(const short8*)&h1c[l15*136 + cc*32 + quad*8];
            f32x4 ba[2] = {fz,fz};
            #pragma unroll
            for (int cc=0;cc<4;cc++){
                ba[0] = __builtin_amdgcn_mfma_f32_16x16x32_bf16(af3[0][cc], hbv[cc], ba[0], 0,0,0);
                ba[1] = __builtin_amdgcn_mfma_f32_16x16x32_bf16(af3[1][cc], hbv[cc], ba[1], 0,0,0);
            }
            *(f32x4*)&z2l[l15*264 + (wave*8 + quad)*4]     = ba[0];
            *(f32x4*)&z2l[l15*264 + (wave*8 + 4 + quad)*4] = ba[1];
            __syncthreads();
            for (int s=0;s<16;s++){
                int sg = c*16 + s;
                const u16* hp2 = hb2[(sg+1)&1];
                short8 g0 = *(const short8*)&hp2[quad*8];
                short8 g1 = *(const short8*)&hp2[32+quad*8];
                f32x4 a0 = __builtin_amdgcn_mfma_f32_16x16x32_bf16(af2[0][0], g0, fz, 0,0,0);
                a0 = __builtin_amdgcn_mfma_f32_16x16x32_bf16(af2[0][1], g1, a0, 0,0,0);
                f32x4 a1 = __builtin_amdgcn_mfma_f32_16x16x32_bf16(af2[1][0], g0, fz, 0,0,0);
                a1 = __builtin_amdgcn_mfma_f32_16x16x32_bf16(af2[1][1], g1, a1, 0,0,0);
                f32x4 z = (l15==1) ? a1 : a0;
                if (l15<2){
                    const float4 pf = *(const float4*)&z2l[s*264 + u2*4];
                    float zi = z[0]+pf.x+bz0;
                    float zf = z[1]+pf.y+bz1;
                    float zg = z[2]+pf.z+bz2;
                    float zo = z[3]+pf.w+bz3;
                    cst = sigm(zf)*cst + sigm(zi)*tanh_(zg);
                    float ho = sigm(zo)*tanh_(cst);
                    hb2[sg&1][u2] = f2b(ho);
                    hf[u2] = ho;
                }
                __syncthreads();
            }
        }
        if (tid<4){
            float acc = b2f(fc_b[tid]);
            #pragma unroll
            for (int j=0;j<64;j++) acc += hf[j]*b2f(fc_w[tid*64+j]);
            if (*flag) ((float*)outv)[tid] = acc;
            else       ((u16*)outv)[tid]  = f2b(acc);
        }
    }
}

// ---------------------------------------------------------------------------
extern "C" void kernel_launch(void* const* d_in, const int* in_sizes, int n_in,
                              void* d_out, int out_size, void* d_ws, size_t ws_size,
                              hipStream_t stream) {
    const int* ei = (const int*)d_in[1];
    char* ws = (char*)d_ws;

    const size_t o_blob = 0;
    const size_t o_h    = 18733184;
    const size_t o_C    = o_h    + 34603008;
    const size_t o_wlrt = o_C    + 69206016;
    const size_t o_ep1  = o_wlrt + 1048576;
    const size_t o_ep2  = o_ep1  + 198656;
    const size_t o_csr  = o_ep2  + 198656;
    const size_t o_pre1 = o_csr  + 2048;
    const size_t o_w1p  = o_pre1 + 2097152;
    const size_t o_w2ip = o_w1p  + 131072;
    const size_t o_w2hp = o_w2ip + 65536;
    const size_t o_ring = o_w2hp + 32768;
    const size_t o_flgs = o_ring + 262144;

    u16*   blob  = (u16*)(ws + o_blob);
    u16*   h_buf = (u16*)(ws + o_h);
    u16*   Cbuf  = (u16*)(ws + o_C);
    u16*   wlrt  = (u16*)(ws + o_wlrt);
    float* ep1   = (float*)(ws + o_ep1);
    float* ep2   = (float*)(ws + o_ep2);
    int*   csr   = (int*)(ws + o_csr);
    int*   flag  = csr + 400;
    float* pre1  = (float*)(ws + o_pre1);
    u16*   w1p   = (u16*)(ws + o_w1p);
    u16*   w2ip  = (u16*)(ws + o_w2ip);
    u16*   w2hp  = (u16*)(ws + o_w2hp);
    u32*   ring  = (u32*)(ws + o_ring);
    u32*   flags = (u32*)(ws + o_flgs);
    float* part  = (float*)(ws + o_C);

    ConvArgs ca;
    const int blob_off[22] = {CX,CEA,CG1WL,CG1WR,CG1WE,CG1ATT,CG1B,
                              CG2WL,CG2WR,CG2WE,CG2ATT,CG2B,
                              CL1WIH,CL1WHH,CL1BIH,CL1BHH,
                              CL2WIH,CL2WHH,CL2BIH,CL2BHH,CFCW,CFCB};
    const int in_idx[22]   = {0,2,3,4,5,6,7,8,9,10,11,12,13,14,15,16,17,18,19,20,21,22};
    for (int s=0;s<22;s++){
        ca.src[s]=d_in[in_idx[s]]; ca.n[s]=in_sizes[in_idx[s]]; ca.off[s]=blob_off[s];
    }
    convert_kernel<<<2048,256,0,stream>>>(ca, (const u32*)d_in[3], flag, blob);

    prep_kernel<<<1089,256,0,stream>>>(ei, blob+CEA, blob+CG1WE, blob+CG2WE,
                                       blob+CG2WL, blob+CG2WR,
                                       blob+CL1WHH, blob+CL2WIH, blob+CL2WHH,
                                       csr, ep1, ep2, wlrt, w1p, w2ip, w2hp);
    gat1_kernel<<<NT,256,0,stream>>>(blob+CX, blob+CG1WL, blob+CG1WR, blob+CG1ATT,
                                     blob+CG1B, ep1, csr, h_buf);
    gemm_nt<<<dim3(8,264,1),256,0,stream>>>(h_buf, wlrt, Cbuf, 33792, 1024, 512, 512, 0);
    gat2_kernel<<<NT,256,0,stream>>>(Cbuf, blob+CG2ATT, blob+CG2B, ep2, csr, h_buf);
    gemm_nt<<<dim3(4,8,16),256,0,stream>>>(h_buf, blob+CL1WIH, part, 1024, 512, 16896, 1056, 1);
    reduce16_kernel<<<2048,256,0,stream>>>(part, blob+CL1BIH, blob+CL1BHH, pre1);
    lstm_fused_kernel<<<2,512,0,stream>>>(pre1,
        w1p, w2ip, w2hp, blob+CL2BIH, blob+CL2BHH,
        blob+CFCW, blob+CFCB, flag, ring, flags, d_out);
}